// Round 2
// baseline (1004.458 us; speedup 1.0000x reference)
//
#include <hip/hip_runtime.h>
#include <hip/hip_bf16.h>
#include <math.h>

typedef __bf16 bf16_t;
typedef __attribute__((ext_vector_type(8))) __bf16 bf16x8;
typedef __attribute__((ext_vector_type(4))) float floatx4;

#define SCALE 0.17677669529663689f

// ---------------------------------------------------------------------------
// Kernel 1: LayerNorm + cyclic shift (-3,-3) + window partition  (fp32)
// one wave per token; lane handles channels c, c+64, c+128
// ---------------------------------------------------------------------------
__global__ __launch_bounds__(256)
void ln_window(const float* __restrict__ x, const float* __restrict__ g,
               const float* __restrict__ bta, float* __restrict__ xw)
{
    const int wv = threadIdx.x >> 6, lane = threadIdx.x & 63;
    const int t = blockIdx.x * 4 + wv;            // token id, < 100352
    const float* row = x + (size_t)t * 192;
    float v0 = row[lane];
    float v1 = row[lane + 64];
    float v2 = row[lane + 128];
    float s  = v0 + v1 + v2;
    float sq = v0 * v0 + v1 * v1 + v2 * v2;
#pragma unroll
    for (int off = 32; off > 0; off >>= 1) {
        s  += __shfl_down(s, off);
        sq += __shfl_down(sq, off);
    }
    s = __shfl(s, 0); sq = __shfl(sq, 0);
    float mu  = s * (1.0f / 192.0f);
    float var = sq * (1.0f / 192.0f) - mu * mu;
    float inv = rsqrtf(var + 1e-5f);

    int b = t / 3136, p = t - b * 3136;
    int hh = p / 56, ww = p - hh * 56;
    int hs = hh - 3; if (hs < 0) hs += 56;
    int ws = ww - 3; if (ws < 0) ws += 56;
    int wh = hs / 7, ii = hs - wh * 7;
    int wwi = ws / 7, jj = ws - wwi * 7;
    size_t orow = ((size_t)(b * 64 + wh * 8 + wwi) * 49 + ii * 7 + jj) * 192;

    xw[orow + lane]       = (v0 - mu) * inv * g[lane]       + bta[lane];
    xw[orow + lane + 64]  = (v1 - mu) * inv * g[lane + 64]  + bta[lane + 64];
    xw[orow + lane + 128] = (v2 - mu) * inv * g[lane + 128] + bta[lane + 128];
}

// ---------------------------------------------------------------------------
// GEMM  C[m][n] = sum_k A[m][k]*W[n][k] (+bias + epilogue), fp32 in/out.
// Internally split-bf16: a = a_hi + a_lo; a*b ~= ah*bh + ah*bl + al*bh
// (rel err ~2^-16, safe for the 0.108 abs threshold at any plausible scale).
// 64x64 block tile; K=192 staged as 2 chunks of 96 (LDS 51KB -> 3 blk/CU).
// mode 0: qkv (scale q, scatter to [B_][NH][3][N][HD] slabs)
// mode 1: proj (window-reverse + unshift scatter to spatial [M][192])
// mode 2: lin  (exact gelu + residual add, write d_out)
// ---------------------------------------------------------------------------
__device__ __forceinline__ void split8(const float* p, bf16x8& hi, bf16x8& lo)
{
#pragma unroll
    for (int j = 0; j < 8; ++j) {
        float f = p[j];
        __bf16 h = (__bf16)f;
        hi[j] = h;
        lo[j] = (__bf16)(f - (float)h);
    }
}

__global__ __launch_bounds__(256)
void gemm_hilo(const float* __restrict__ A, const float* __restrict__ W,
               const float* __restrict__ bias, const float* __restrict__ resid,
               float* __restrict__ out, int mode)
{
    __shared__ __align__(16) float ldsA[64][100];   // 96 + 4 pad
    __shared__ __align__(16) float ldsW[64][100];
    const int tid = threadIdx.x;
    const int m0 = blockIdx.x * 64;
    const int n0 = blockIdx.y * 64;
    const int wave = tid >> 6, lane = tid & 63;
    const int quad = lane >> 4, lr = lane & 15;

    floatx4 acc[4] = {{0.f,0.f,0.f,0.f},{0.f,0.f,0.f,0.f},{0.f,0.f,0.f,0.f},{0.f,0.f,0.f,0.f}};

    for (int kc = 0; kc < 2; ++kc) {
        // stage 64 rows x 96 cols fp32 = 1536 float4 per tile
        for (int i = tid; i < 1536; i += 256) {
            int row = i / 24, c4 = i % 24;
            *(float4*)&ldsA[row][c4 * 4] =
                *(const float4*)(A + (size_t)(m0 + row) * 192 + kc * 96 + c4 * 4);
        }
        for (int i = tid; i < 1536; i += 256) {
            int row = i / 24, c4 = i % 24;
            *(float4*)&ldsW[row][c4 * 4] =
                *(const float4*)(W + (size_t)(n0 + row) * 192 + kc * 96 + c4 * 4);
        }
        __syncthreads();

#pragma unroll
        for (int ks = 0; ks < 3; ++ks) {
            bf16x8 ahi, alo;
            split8(&ldsA[wave * 16 + lr][ks * 32 + quad * 8], ahi, alo);
#pragma unroll
            for (int nt = 0; nt < 4; ++nt) {
                bf16x8 whi, wlo;
                split8(&ldsW[nt * 16 + lr][ks * 32 + quad * 8], whi, wlo);
                acc[nt] = __builtin_amdgcn_mfma_f32_16x16x32_bf16(ahi, whi, acc[nt], 0, 0, 0);
                acc[nt] = __builtin_amdgcn_mfma_f32_16x16x32_bf16(ahi, wlo, acc[nt], 0, 0, 0);
                acc[nt] = __builtin_amdgcn_mfma_f32_16x16x32_bf16(alo, whi, acc[nt], 0, 0, 0);
            }
        }
        __syncthreads();
    }

#pragma unroll
    for (int nt = 0; nt < 4; ++nt) {
        int n = n0 + nt * 16 + lr;
        float bv = bias[n];
#pragma unroll
        for (int r = 0; r < 4; ++r) {
            int m = m0 + wave * 16 + quad * 4 + r;
            float val = acc[nt][r] + bv;
            if (mode == 0) {
                int which = n / 192;
                int rem = n - which * 192;
                int hh = rem >> 5, d = rem & 31;
                if (which == 0) val *= SCALE;
                int b_ = m / 49, tok = m - b_ * 49;
                size_t dst = ((((size_t)b_ * 6 + hh) * 3 + which) * 49 + tok) * 32 + d;
                out[dst] = val;
            } else if (mode == 1) {
                int b_ = m / 49, tok = m - b_ * 49;
                int b = b_ >> 6, widx = b_ & 63;
                int wh = widx >> 3, ww = widx & 7;
                int ii = tok / 7, jj = tok - ii * 7;
                int hs = wh * 7 + ii + 3; if (hs >= 56) hs -= 56;
                int ws2 = ww * 7 + jj + 3; if (ws2 >= 56) ws2 -= 56;
                size_t dst = ((size_t)(b * 3136 + hs * 56 + ws2)) * 192 + n;
                out[dst] = val;
            } else {
                float gx = 0.5f * val * (1.0f + erff(val * 0.70710678118654752f));
                out[(size_t)m * 192 + n] = resid[(size_t)m * 192 + n] + gx;
            }
        }
    }
}

// ---------------------------------------------------------------------------
// Kernel 3: window attention, one block per (window, head), all fp32.
// qkv slab per (window,head): [3][49][32] f32 contiguous (4704 floats)
// ---------------------------------------------------------------------------
__global__ __launch_bounds__(256)
void attn_kernel(const float* __restrict__ qkv, const float* __restrict__ table,
                 const int* __restrict__ rpi, const float* __restrict__ mask,
                 float* __restrict__ ctx)
{
    __shared__ float qkv_s[4704];
    __shared__ float S[2401];
    const int tid = threadIdx.x;
    const int bh = blockIdx.x;
    const int b_ = bh / 6, h = bh - b_ * 6;

    const float4* src = (const float4*)(qkv + (size_t)bh * 4704);
    for (int i = tid; i < 1176; i += 256) {
        float4 v4 = src[i];
        qkv_s[i * 4 + 0] = v4.x; qkv_s[i * 4 + 1] = v4.y;
        qkv_s[i * 4 + 2] = v4.z; qkv_s[i * 4 + 3] = v4.w;
    }
    __syncthreads();

    const float* q = qkv_s;
    const float* k = qkv_s + 1568;
    const float* v = qkv_s + 3136;
    const int win = b_ & 63;

    for (int s = tid; s < 2401; s += 256) {
        int i = s / 49, j = s - i * 49;
        float dot = 0.f;
#pragma unroll 8
        for (int d = 0; d < 32; ++d) dot += q[i * 32 + d] * k[j * 32 + d];
        dot += table[rpi[s] * 6 + h];
        dot += mask[(size_t)win * 2401 + s];
        S[s] = dot;
    }
    __syncthreads();

    if (tid < 49) {
        float mx = -1e30f;
        for (int j = 0; j < 49; ++j) mx = fmaxf(mx, S[tid * 49 + j]);
        float sum = 0.f;
        for (int j = 0; j < 49; ++j) {
            float e = __expf(S[tid * 49 + j] - mx);
            S[tid * 49 + j] = e; sum += e;
        }
        float inv = 1.0f / sum;
        for (int j = 0; j < 49; ++j) S[tid * 49 + j] *= inv;
    }
    __syncthreads();

    for (int o = tid; o < 1568; o += 256) {
        int i = o >> 5, d = o & 31;
        float sum = 0.f;
        for (int j = 0; j < 49; ++j) sum += S[i * 49 + j] * v[j * 32 + d];
        ctx[((size_t)b_ * 49 + i) * 192 + h * 32 + d] = sum;
    }
}

// ---------------------------------------------------------------------------
extern "C" void kernel_launch(void* const* d_in, const int* in_sizes, int n_in,
                              void* d_out, int out_size, void* d_ws, size_t ws_size,
                              hipStream_t stream)
{
    const float* inp    = (const float*)d_in[0];
    const float* mask   = (const float*)d_in[1];
    const float* g      = (const float*)d_in[2];
    const float* bta    = (const float*)d_in[3];
    const float* qkv_w  = (const float*)d_in[4];
    const float* qkv_b  = (const float*)d_in[5];
    const float* table  = (const float*)d_in[6];
    const int*   rpi    = (const int*)d_in[7];
    const float* proj_w = (const float*)d_in[8];
    const float* proj_b = (const float*)d_in[9];
    const float* lin_w  = (const float*)d_in[10];
    const float* lin_b  = (const float*)d_in[11];
    float* out = (float*)d_out;

    char* ws = (char*)d_ws;
    float* xw   = (float*)(ws);                 // 77,070,336 B; reused as ctx
    float* qkvb = (float*)(ws + 77070336);      // 231,211,008 B; reused as proj-out
    // total ws use: 308,281,344 B

    ln_window<<<25088, 256, 0, stream>>>(inp, g, bta, xw);
    gemm_hilo<<<dim3(1568, 9), 256, 0, stream>>>(xw, qkv_w, qkv_b, nullptr, qkvb, 0);
    attn_kernel<<<12288, 256, 0, stream>>>(qkvb, table, rpi, mask, xw);
    gemm_hilo<<<dim3(1568, 3), 256, 0, stream>>>(xw, proj_w, proj_b, nullptr, qkvb, 1);
    gemm_hilo<<<dim3(1568, 3), 256, 0, stream>>>(qkvb, lin_w, lin_b, inp, out, 2);
}

// Round 3
// 509.227 us; speedup vs baseline: 1.9725x; 1.9725x over previous
//
#include <hip/hip_runtime.h>
#include <hip/hip_bf16.h>
#include <math.h>

typedef __bf16 bf16_t;
typedef __attribute__((ext_vector_type(8))) __bf16 bf16x8;
typedef __attribute__((ext_vector_type(4))) float floatx4;

#define SCALE 0.17677669529663689f

// ---------------------------------------------------------------------------
// LayerNorm + cyclic shift (-3,-3) + window partition; fp32 in -> bf16 out
// ---------------------------------------------------------------------------
__global__ __launch_bounds__(256)
void ln_window(const float* __restrict__ x, const float* __restrict__ g,
               const float* __restrict__ bta, bf16_t* __restrict__ xw)
{
    const int wv = threadIdx.x >> 6, lane = threadIdx.x & 63;
    const int t = blockIdx.x * 4 + wv;            // token id, < 100352
    const float* row = x + (size_t)t * 192;
    float v0 = row[lane];
    float v1 = row[lane + 64];
    float v2 = row[lane + 128];
    float s  = v0 + v1 + v2;
    float sq = v0 * v0 + v1 * v1 + v2 * v2;
#pragma unroll
    for (int off = 32; off > 0; off >>= 1) {
        s  += __shfl_down(s, off);
        sq += __shfl_down(sq, off);
    }
    s = __shfl(s, 0); sq = __shfl(sq, 0);
    float mu  = s * (1.0f / 192.0f);
    float var = sq * (1.0f / 192.0f) - mu * mu;
    float inv = rsqrtf(var + 1e-5f);

    int b = t / 3136, p = t - b * 3136;
    int hh = p / 56, ww = p - hh * 56;
    int hs = hh - 3; if (hs < 0) hs += 56;
    int ws = ww - 3; if (ws < 0) ws += 56;
    int wh = hs / 7, ii = hs - wh * 7;
    int wwi = ws / 7, jj = ws - wwi * 7;
    size_t orow = ((size_t)(b * 64 + wh * 8 + wwi) * 49 + ii * 7 + jj) * 192;

    xw[orow + lane]       = (bf16_t)((v0 - mu) * inv * g[lane]       + bta[lane]);
    xw[orow + lane + 64]  = (bf16_t)((v1 - mu) * inv * g[lane + 64]  + bta[lane + 64]);
    xw[orow + lane + 128] = (bf16_t)((v2 - mu) * inv * g[lane + 128] + bta[lane + 128]);
}

// ---------------------------------------------------------------------------
// Weight fp32 -> bf16 conversion (qkv_w | proj_w | lin_w concatenated)
// ---------------------------------------------------------------------------
__global__ __launch_bounds__(256)
void convert_weights(const float* __restrict__ a, const float* __restrict__ b,
                     const float* __restrict__ c, bf16_t* __restrict__ out)
{
    int i = blockIdx.x * 256 + threadIdx.x;   // 184320 total
    if (i < 110592)       out[i] = (bf16_t)a[i];
    else if (i < 147456)  out[i] = (bf16_t)b[i - 110592];
    else                  out[i] = (bf16_t)c[i - 147456];
}

// ---------------------------------------------------------------------------
// Pre-combine rel-pos bias + shift mask into C-fragment-ordered table:
// cb2[wh=win*6+h][mt][lane][nt*4+r]  (bf16), value for S row m=mt*16+(lane>>4)*4+r,
// col j=nt*16+(lane&15). j>=49 -> -1e30 (pad cols killed in softmax).
// ---------------------------------------------------------------------------
__global__ __launch_bounds__(256)
void build_cb2(const float* __restrict__ table, const int* __restrict__ rpi,
               const float* __restrict__ mask, bf16_t* __restrict__ cb2)
{
    int i = blockIdx.x * 256 + threadIdx.x;   // 1,572,864 total
    int idx = i & 15, lane = (i >> 4) & 63, mt = (i >> 10) & 3, wh = i >> 12;
    int win = wh / 6, h = wh - win * 6;
    int nt = idx >> 2, r = idx & 3;
    int m = mt * 16 + ((lane >> 4)) * 4 + r;
    int j = nt * 16 + (lane & 15);
    float v;
    if (j >= 49)      v = -1e30f;
    else if (m >= 49) v = 0.0f;
    else              v = table[rpi[m * 49 + j] * 6 + h] + mask[win * 2401 + m * 49 + j];
    cb2[i] = (bf16_t)v;
}

// ---------------------------------------------------------------------------
// GEMM  C[m][n] = sum_k A[m][k]*W[n][k] + bias, bf16 in, mfma_f32_16x16x32_bf16.
// 64x64 tile, K=192 resident. grid: (n_blocks, m_blocks).
// mode 0: qkv -> q (scaled) / k slabs [pair][49][32] + v transposed [pair][32][64]
// mode 1: proj -> window-reverse + unshift scatter, bf16 spatial [M][192]
// mode 2: lin  -> exact gelu + fp32 residual, fp32 d_out
// ---------------------------------------------------------------------------
__global__ __launch_bounds__(256)
void gemm_bf16(const bf16_t* __restrict__ A, const bf16_t* __restrict__ W,
               const float* __restrict__ bias, const float* __restrict__ resid,
               bf16_t* __restrict__ ob0, bf16_t* __restrict__ ob1,
               bf16_t* __restrict__ ob2, float* __restrict__ of, int mode)
{
    __shared__ __align__(16) bf16_t ldsA[64][200];
    __shared__ __align__(16) bf16_t ldsW[64][200];
    const int tid = threadIdx.x;
    const int n0 = blockIdx.x * 64;
    const int m0 = blockIdx.y * 64;

    for (int i = tid; i < 1536; i += 256) {
        int row = i / 24, c8 = i % 24;
        *(uint4*)&ldsA[row][c8 * 8] = *(const uint4*)(A + (size_t)(m0 + row) * 192 + c8 * 8);
    }
    for (int i = tid; i < 1536; i += 256) {
        int row = i / 24, c8 = i % 24;
        *(uint4*)&ldsW[row][c8 * 8] = *(const uint4*)(W + (size_t)(n0 + row) * 192 + c8 * 8);
    }
    __syncthreads();

    const int wave = tid >> 6, lane = tid & 63;
    const int quad = lane >> 4, lr = lane & 15;

    floatx4 acc[4] = {{0.f,0.f,0.f,0.f},{0.f,0.f,0.f,0.f},{0.f,0.f,0.f,0.f},{0.f,0.f,0.f,0.f}};
#pragma unroll
    for (int ks = 0; ks < 6; ++ks) {
        bf16x8 af = *(const bf16x8*)&ldsA[wave * 16 + lr][ks * 32 + quad * 8];
#pragma unroll
        for (int nt = 0; nt < 4; ++nt) {
            bf16x8 wf = *(const bf16x8*)&ldsW[nt * 16 + lr][ks * 32 + quad * 8];
            acc[nt] = __builtin_amdgcn_mfma_f32_16x16x32_bf16(af, wf, acc[nt], 0, 0, 0);
        }
    }

#pragma unroll
    for (int nt = 0; nt < 4; ++nt) {
        int n = n0 + nt * 16 + lr;
        float bv = bias[n];
#pragma unroll
        for (int r = 0; r < 4; ++r) {
            int m = m0 + wave * 16 + quad * 4 + r;
            float val = acc[nt][r] + bv;
            if (mode == 0) {
                int which = n / 192;              // 0=q 1=k 2=v
                int rem = n - which * 192;
                int hh = rem >> 5, d = rem & 31;
                int b_ = m / 49, tok = m - b_ * 49;
                int pair = b_ * 6 + hh;
                if (which == 0)
                    ob0[((size_t)pair * 49 + tok) * 32 + d] = (bf16_t)(val * SCALE);
                else if (which == 1)
                    ob1[((size_t)pair * 49 + tok) * 32 + d] = (bf16_t)val;
                else
                    ob2[((size_t)pair * 32 + d) * 64 + tok] = (bf16_t)val;
            } else if (mode == 1) {
                int b_ = m / 49, tok = m - b_ * 49;
                int b = b_ >> 6, widx = b_ & 63;
                int wh = widx >> 3, ww = widx & 7;
                int ii = tok / 7, jj = tok - ii * 7;
                int hs = wh * 7 + ii + 3; if (hs >= 56) hs -= 56;
                int ws2 = ww * 7 + jj + 3; if (ws2 >= 56) ws2 -= 56;
                ob0[((size_t)(b * 3136 + hs * 56 + ws2)) * 192 + n] = (bf16_t)val;
            } else {
                float gx = 0.5f * val * (1.0f + erff(val * 0.70710678118654752f));
                of[(size_t)m * 192 + n] = resid[(size_t)m * 192 + n] + gx;
            }
        }
    }
}

// ---------------------------------------------------------------------------
// MFMA window attention: one wave per (window,head) pair; 4 pairs per block.
// QK^T (16 mfma, 64x64 padded) -> +bias/mask (cb2) -> in-register softmax
// (shfl_xor over 16-lane col group) -> P via wave-private LDS (A-layout)
// -> PV (16 mfma) -> ctx [M][192] bf16.
// ---------------------------------------------------------------------------
__global__ __launch_bounds__(256)
void attn_mfma(const bf16_t* __restrict__ qbuf, const bf16_t* __restrict__ kbuf,
               const bf16_t* __restrict__ vtbuf, const bf16_t* __restrict__ cb2,
               bf16_t* __restrict__ ctx)
{
    __shared__ __align__(16) bf16_t Plds[4][64][72];   // stride 72: conflict-free b128
    const int tid = threadIdx.x;
    const int wave = tid >> 6, lane = tid & 63;
    const int quad = lane >> 4, lr = lane & 15;
    const int p = blockIdx.x * 4 + wave;               // pair id < 12288
    const int b_ = p / 6, h = p - b_ * 6;
    const int wh = (b_ & 63) * 6 + h;

    const bf16_t* qs = qbuf + (size_t)p * 1568;
    const bf16_t* ks = kbuf + (size_t)p * 1568;

    bf16x8 qf[4], kf[4];
#pragma unroll
    for (int t = 0; t < 4; ++t) {
        qf[t] = *(const bf16x8*)(qs + (t * 16 + lr) * 32 + quad * 8);
        kf[t] = *(const bf16x8*)(ks + (t * 16 + lr) * 32 + quad * 8);
    }

    floatx4 acc[4][4];
#pragma unroll
    for (int mt = 0; mt < 4; ++mt)
#pragma unroll
        for (int nt = 0; nt < 4; ++nt)
            acc[mt][nt] = floatx4{0.f, 0.f, 0.f, 0.f};

#pragma unroll
    for (int mt = 0; mt < 4; ++mt)
#pragma unroll
        for (int nt = 0; nt < 4; ++nt)
            acc[mt][nt] = __builtin_amdgcn_mfma_f32_16x16x32_bf16(qf[mt], kf[nt], acc[mt][nt], 0, 0, 0);

    // bias + mask (C-frag ordered)
    const bf16_t* cb = cb2 + (((size_t)wh * 4) * 64 + lane) * 16;
#pragma unroll
    for (int mt = 0; mt < 4; ++mt) {
        bf16x8 c0 = *(const bf16x8*)(cb + (size_t)mt * 1024);
        bf16x8 c1 = *(const bf16x8*)(cb + (size_t)mt * 1024 + 8);
#pragma unroll
        for (int r = 0; r < 4; ++r) {
            acc[mt][0][r] += (float)c0[r];
            acc[mt][1][r] += (float)c0[4 + r];
            acc[mt][2][r] += (float)c1[r];
            acc[mt][3][r] += (float)c1[4 + r];
        }
    }

    // in-register row softmax (row spread over 16 lr lanes x 4 nt regs)
#pragma unroll
    for (int mt = 0; mt < 4; ++mt) {
#pragma unroll
        for (int r = 0; r < 4; ++r) {
            float mx = fmaxf(fmaxf(acc[mt][0][r], acc[mt][1][r]),
                             fmaxf(acc[mt][2][r], acc[mt][3][r]));
#pragma unroll
            for (int off = 1; off < 16; off <<= 1)
                mx = fmaxf(mx, __shfl_xor(mx, off));
            float s = 0.f;
#pragma unroll
            for (int nt = 0; nt < 4; ++nt) {
                float e = __expf(acc[mt][nt][r] - mx);
                acc[mt][nt][r] = e; s += e;
            }
#pragma unroll
            for (int off = 1; off < 16; off <<= 1)
                s += __shfl_xor(s, off);
            float inv = 1.0f / s;
#pragma unroll
            for (int nt = 0; nt < 4; ++nt) acc[mt][nt][r] *= inv;
        }
    }

    // P: C-layout -> A-layout via wave-private LDS tile
#pragma unroll
    for (int mt = 0; mt < 4; ++mt)
#pragma unroll
        for (int nt = 0; nt < 4; ++nt)
#pragma unroll
            for (int r = 0; r < 4; ++r)
                Plds[wave][mt * 16 + quad * 4 + r][nt * 16 + lr] = (bf16_t)acc[mt][nt][r];
    __syncthreads();

    // PV
    const bf16_t* vs = vtbuf + (size_t)p * 2048;
    bf16x8 vf[2][2];
#pragma unroll
    for (int nt = 0; nt < 2; ++nt)
#pragma unroll
        for (int kt = 0; kt < 2; ++kt)
            vf[nt][kt] = *(const bf16x8*)(vs + (nt * 16 + lr) * 64 + kt * 32 + quad * 8);

#pragma unroll
    for (int mt = 0; mt < 4; ++mt) {
        bf16x8 pf0 = *(const bf16x8*)&Plds[wave][mt * 16 + lr][quad * 8];
        bf16x8 pf1 = *(const bf16x8*)&Plds[wave][mt * 16 + lr][32 + quad * 8];
        floatx4 cacc[2] = {{0.f,0.f,0.f,0.f},{0.f,0.f,0.f,0.f}};
#pragma unroll
        for (int nt = 0; nt < 2; ++nt) {
            cacc[nt] = __builtin_amdgcn_mfma_f32_16x16x32_bf16(pf0, vf[nt][0], cacc[nt], 0, 0, 0);
            cacc[nt] = __builtin_amdgcn_mfma_f32_16x16x32_bf16(pf1, vf[nt][1], cacc[nt], 0, 0, 0);
        }
#pragma unroll
        for (int nt = 0; nt < 2; ++nt)
#pragma unroll
            for (int r = 0; r < 4; ++r) {
                int m = mt * 16 + quad * 4 + r;
                if (m < 49)
                    ctx[((size_t)b_ * 49 + m) * 192 + h * 32 + nt * 16 + lr] = (bf16_t)cacc[nt][r];
            }
    }
}

// ---------------------------------------------------------------------------
extern "C" void kernel_launch(void* const* d_in, const int* in_sizes, int n_in,
                              void* d_out, int out_size, void* d_ws, size_t ws_size,
                              hipStream_t stream)
{
    const float* inp    = (const float*)d_in[0];
    const float* mask   = (const float*)d_in[1];
    const float* g      = (const float*)d_in[2];
    const float* bta    = (const float*)d_in[3];
    const float* qkv_w  = (const float*)d_in[4];
    const float* qkv_b  = (const float*)d_in[5];
    const float* table  = (const float*)d_in[6];
    const int*   rpi    = (const int*)d_in[7];
    const float* proj_w = (const float*)d_in[8];
    const float* proj_b = (const float*)d_in[9];
    const float* lin_w  = (const float*)d_in[10];
    const float* lin_b  = (const float*)d_in[11];
    float* out = (float*)d_out;

    char* ws = (char*)d_ws;
    bf16_t* xw   = (bf16_t*)(ws);                    //  38,535,168 B
    bf16_t* qb   = (bf16_t*)(ws + 38535168);         //  38,535,168 B
    bf16_t* kb   = (bf16_t*)(ws + 77070336);         //  38,535,168 B
    bf16_t* vt   = (bf16_t*)(ws + 115605504);        //  50,331,648 B
    bf16_t* ctxb = (bf16_t*)(ws + 165937152);        //  38,535,168 B
    bf16_t* pob  = (bf16_t*)(ws + 204472320);        //  38,535,168 B
    bf16_t* wcvt = (bf16_t*)(ws + 243007488);        //     368,640 B
    bf16_t* cb2  = (bf16_t*)(ws + 243376128);        //   3,145,728 B  (end 246.5 MB)

    convert_weights<<<720, 256, 0, stream>>>(qkv_w, proj_w, lin_w, wcvt);
    build_cb2<<<6144, 256, 0, stream>>>(table, rpi, mask, cb2);
    ln_window<<<25088, 256, 0, stream>>>(inp, g, bta, xw);
    gemm_bf16<<<dim3(9, 1568), 256, 0, stream>>>(xw, wcvt, qkv_b, nullptr,
                                                 qb, kb, vt, nullptr, 0);
    attn_mfma<<<3072, 256, 0, stream>>>(qb, kb, vt, cb2, ctxb);
    gemm_bf16<<<dim3(3, 1568), 256, 0, stream>>>(ctxb, wcvt + 110592, proj_b, nullptr,
                                                 pob, nullptr, nullptr, nullptr, 1);
    gemm_bf16<<<dim3(3, 1568), 256, 0, stream>>>(pob, wcvt + 147456, lin_b, inp,
                                                 nullptr, nullptr, nullptr, out, 2);
}

// Round 4
// 503.069 us; speedup vs baseline: 1.9967x; 1.0122x over previous
//
#include <hip/hip_runtime.h>
#include <hip/hip_bf16.h>
#include <math.h>

typedef __bf16 bf16_t;
typedef __attribute__((ext_vector_type(8))) __bf16 bf16x8;
typedef __attribute__((ext_vector_type(4))) float floatx4;

#define SCALE 0.17677669529663689f

// ---------------------------------------------------------------------------
// LayerNorm + cyclic shift (-3,-3) + window partition; fp32 in -> bf16 out
// ---------------------------------------------------------------------------
__global__ __launch_bounds__(256)
void ln_window(const float* __restrict__ x, const float* __restrict__ g,
               const float* __restrict__ bta, bf16_t* __restrict__ xw)
{
    const int wv = threadIdx.x >> 6, lane = threadIdx.x & 63;
    const int t = blockIdx.x * 4 + wv;            // token id, < 100352
    const float* row = x + (size_t)t * 192;
    float v0 = row[lane];
    float v1 = row[lane + 64];
    float v2 = row[lane + 128];
    float s  = v0 + v1 + v2;
    float sq = v0 * v0 + v1 * v1 + v2 * v2;
#pragma unroll
    for (int off = 32; off > 0; off >>= 1) {
        s  += __shfl_down(s, off);
        sq += __shfl_down(sq, off);
    }
    s = __shfl(s, 0); sq = __shfl(sq, 0);
    float mu  = s * (1.0f / 192.0f);
    float var = sq * (1.0f / 192.0f) - mu * mu;
    float inv = rsqrtf(var + 1e-5f);

    int b = t / 3136, p = t - b * 3136;
    int hh = p / 56, ww = p - hh * 56;
    int hs = hh - 3; if (hs < 0) hs += 56;
    int ws = ww - 3; if (ws < 0) ws += 56;
    int wh = hs / 7, ii = hs - wh * 7;
    int wwi = ws / 7, jj = ws - wwi * 7;
    size_t orow = ((size_t)(b * 64 + wh * 8 + wwi) * 49 + ii * 7 + jj) * 192;

    xw[orow + lane]       = (bf16_t)((v0 - mu) * inv * g[lane]       + bta[lane]);
    xw[orow + lane + 64]  = (bf16_t)((v1 - mu) * inv * g[lane + 64]  + bta[lane + 64]);
    xw[orow + lane + 128] = (bf16_t)((v2 - mu) * inv * g[lane + 128] + bta[lane + 128]);
}

// ---------------------------------------------------------------------------
// Weight fp32 -> bf16 conversion (qkv_w | proj_w | lin_w concatenated)
// ---------------------------------------------------------------------------
__global__ __launch_bounds__(256)
void convert_weights(const float* __restrict__ a, const float* __restrict__ b,
                     const float* __restrict__ c, bf16_t* __restrict__ out)
{
    int i = blockIdx.x * 256 + threadIdx.x;   // 184320 total
    if (i < 110592)       out[i] = (bf16_t)a[i];
    else if (i < 147456)  out[i] = (bf16_t)b[i - 110592];
    else                  out[i] = (bf16_t)c[i - 147456];
}

// ---------------------------------------------------------------------------
// Pre-combine rel-pos bias + shift mask into C-fragment-ordered table:
// cb2[wh=win*6+h][mt][lane][nt*4+r]  (bf16)
// ---------------------------------------------------------------------------
__global__ __launch_bounds__(256)
void build_cb2(const float* __restrict__ table, const int* __restrict__ rpi,
               const float* __restrict__ mask, bf16_t* __restrict__ cb2)
{
    int i = blockIdx.x * 256 + threadIdx.x;   // 1,572,864 total
    int idx = i & 15, lane = (i >> 4) & 63, mt = (i >> 10) & 3, wh = i >> 12;
    int win = wh / 6, h = wh - win * 6;
    int nt = idx >> 2, r = idx & 3;
    int m = mt * 16 + ((lane >> 4)) * 4 + r;
    int j = nt * 16 + (lane & 15);
    float v;
    if (j >= 49)      v = -1e30f;
    else if (m >= 49) v = 0.0f;
    else              v = table[rpi[m * 49 + j] * 6 + h] + mask[win * 2401 + m * 49 + j];
    cb2[i] = (bf16_t)v;
}

// ---------------------------------------------------------------------------
// LDS-free GEMM  C[m][n] = sum_k A[m][k]*W[n][k] + bias.
// A,W fragments loaded straight from global (16B/lane, 64B-contiguous rows;
// W is 221KB -> L2-resident broadcast). No barriers, no LDS, no conflicts.
// Block: 4 waves, tile 128m x 64n; wave tile 32m x 64n. grid (nb, 784).
// mode 0: qkv -> q*SCALE / k slabs [pair][49][32] + v transposed [pair][32][64]
// mode 1: proj -> window-reverse + unshift scatter, bf16 spatial [M][192]
// mode 2: lin  -> exact gelu + fp32 residual, fp32 d_out
// ---------------------------------------------------------------------------
__global__ __launch_bounds__(256)
void gemm_bf16(const bf16_t* __restrict__ A, const bf16_t* __restrict__ W,
               const float* __restrict__ bias, const float* __restrict__ resid,
               bf16_t* __restrict__ ob0, bf16_t* __restrict__ ob1,
               bf16_t* __restrict__ ob2, float* __restrict__ of, int mode)
{
    const int tid = threadIdx.x;
    const int wave = tid >> 6, lane = tid & 63;
    const int quad = lane >> 4, lr = lane & 15;
    const int n0 = blockIdx.x * 64;
    const int m0 = blockIdx.y * 128 + wave * 32;

    const bf16_t* a0p = A + (size_t)(m0 + lr) * 192 + quad * 8;
    const bf16_t* a1p = A + (size_t)(m0 + 16 + lr) * 192 + quad * 8;
    const bf16_t* w0p = W + (size_t)(n0 + lr) * 192 + quad * 8;
    const bf16_t* w1p = w0p + 16 * 192;
    const bf16_t* w2p = w0p + 32 * 192;
    const bf16_t* w3p = w0p + 48 * 192;

    floatx4 acc[2][4];
#pragma unroll
    for (int mt = 0; mt < 2; ++mt)
#pragma unroll
        for (int nt = 0; nt < 4; ++nt)
            acc[mt][nt] = floatx4{0.f, 0.f, 0.f, 0.f};

#pragma unroll
    for (int ks = 0; ks < 6; ++ks) {
        bf16x8 af0 = *(const bf16x8*)(a0p + ks * 32);
        bf16x8 af1 = *(const bf16x8*)(a1p + ks * 32);
        bf16x8 wf0 = *(const bf16x8*)(w0p + ks * 32);
        bf16x8 wf1 = *(const bf16x8*)(w1p + ks * 32);
        bf16x8 wf2 = *(const bf16x8*)(w2p + ks * 32);
        bf16x8 wf3 = *(const bf16x8*)(w3p + ks * 32);
        acc[0][0] = __builtin_amdgcn_mfma_f32_16x16x32_bf16(af0, wf0, acc[0][0], 0, 0, 0);
        acc[1][0] = __builtin_amdgcn_mfma_f32_16x16x32_bf16(af1, wf0, acc[1][0], 0, 0, 0);
        acc[0][1] = __builtin_amdgcn_mfma_f32_16x16x32_bf16(af0, wf1, acc[0][1], 0, 0, 0);
        acc[1][1] = __builtin_amdgcn_mfma_f32_16x16x32_bf16(af1, wf1, acc[1][1], 0, 0, 0);
        acc[0][2] = __builtin_amdgcn_mfma_f32_16x16x32_bf16(af0, wf2, acc[0][2], 0, 0, 0);
        acc[1][2] = __builtin_amdgcn_mfma_f32_16x16x32_bf16(af1, wf2, acc[1][2], 0, 0, 0);
        acc[0][3] = __builtin_amdgcn_mfma_f32_16x16x32_bf16(af0, wf3, acc[0][3], 0, 0, 0);
        acc[1][3] = __builtin_amdgcn_mfma_f32_16x16x32_bf16(af1, wf3, acc[1][3], 0, 0, 0);
    }

#pragma unroll
    for (int mt = 0; mt < 2; ++mt)
#pragma unroll
    for (int nt = 0; nt < 4; ++nt) {
        int n = n0 + nt * 16 + lr;
        float bv = bias[n];
#pragma unroll
        for (int r = 0; r < 4; ++r) {
            int m = m0 + mt * 16 + quad * 4 + r;
            float val = acc[mt][nt][r] + bv;
            if (mode == 0) {
                int which = n / 192;              // 0=q 1=k 2=v
                int rem = n - which * 192;
                int hh = rem >> 5, d = rem & 31;
                int b_ = m / 49, tok = m - b_ * 49;
                int pair = b_ * 6 + hh;
                if (which == 0)
                    ob0[((size_t)pair * 49 + tok) * 32 + d] = (bf16_t)(val * SCALE);
                else if (which == 1)
                    ob1[((size_t)pair * 49 + tok) * 32 + d] = (bf16_t)val;
                else
                    ob2[((size_t)pair * 32 + d) * 64 + tok] = (bf16_t)val;
            } else if (mode == 1) {
                int b_ = m / 49, tok = m - b_ * 49;
                int b = b_ >> 6, widx = b_ & 63;
                int wh = widx >> 3, ww = widx & 7;
                int ii = tok / 7, jj = tok - ii * 7;
                int hs = wh * 7 + ii + 3; if (hs >= 56) hs -= 56;
                int ws2 = ww * 7 + jj + 3; if (ws2 >= 56) ws2 -= 56;
                ob0[((size_t)(b * 3136 + hs * 56 + ws2)) * 192 + n] = (bf16_t)val;
            } else {
                float gx = 0.5f * val * (1.0f + erff(val * 0.70710678118654752f));
                of[(size_t)m * 192 + n] = resid[(size_t)m * 192 + n] + gx;
            }
        }
    }
}

// ---------------------------------------------------------------------------
// MFMA window attention: one wave per (window,head) pair; 4 pairs per block.
// QK^T (16 mfma, 64x64 padded) -> +bias/mask (cb2) -> in-register softmax
// -> P via wave-PRIVATE LDS tile (no barrier needed) -> PV -> ctx bf16.
// ---------------------------------------------------------------------------
__global__ __launch_bounds__(256)
void attn_mfma(const bf16_t* __restrict__ qbuf, const bf16_t* __restrict__ kbuf,
               const bf16_t* __restrict__ vtbuf, const bf16_t* __restrict__ cb2,
               bf16_t* __restrict__ ctx)
{
    __shared__ __align__(16) bf16_t Plds[4][64][72];   // wave-private tiles
    const int tid = threadIdx.x;
    const int wave = tid >> 6, lane = tid & 63;
    const int quad = lane >> 4, lr = lane & 15;
    const int p = blockIdx.x * 4 + wave;               // pair id < 12288
    const int b_ = p / 6, h = p - b_ * 6;
    const int wh = (b_ & 63) * 6 + h;

    const bf16_t* qs = qbuf + (size_t)p * 1568;
    const bf16_t* ks = kbuf + (size_t)p * 1568;

    bf16x8 qf[4], kf[4];
#pragma unroll
    for (int t = 0; t < 4; ++t) {
        qf[t] = *(const bf16x8*)(qs + (t * 16 + lr) * 32 + quad * 8);
        kf[t] = *(const bf16x8*)(ks + (t * 16 + lr) * 32 + quad * 8);
    }

    floatx4 acc[4][4];
#pragma unroll
    for (int mt = 0; mt < 4; ++mt)
#pragma unroll
        for (int nt = 0; nt < 4; ++nt)
            acc[mt][nt] = floatx4{0.f, 0.f, 0.f, 0.f};

#pragma unroll
    for (int mt = 0; mt < 4; ++mt)
#pragma unroll
        for (int nt = 0; nt < 4; ++nt)
            acc[mt][nt] = __builtin_amdgcn_mfma_f32_16x16x32_bf16(qf[mt], kf[nt], acc[mt][nt], 0, 0, 0);

    // bias + mask (C-frag ordered)
    const bf16_t* cb = cb2 + (((size_t)wh * 4) * 64 + lane) * 16;
#pragma unroll
    for (int mt = 0; mt < 4; ++mt) {
        bf16x8 c0 = *(const bf16x8*)(cb + (size_t)mt * 1024);
        bf16x8 c1 = *(const bf16x8*)(cb + (size_t)mt * 1024 + 8);
#pragma unroll
        for (int r = 0; r < 4; ++r) {
            acc[mt][0][r] += (float)c0[r];
            acc[mt][1][r] += (float)c0[4 + r];
            acc[mt][2][r] += (float)c1[r];
            acc[mt][3][r] += (float)c1[4 + r];
        }
    }

    // in-register row softmax (row spread over 16 lr lanes x 4 nt regs)
#pragma unroll
    for (int mt = 0; mt < 4; ++mt) {
#pragma unroll
        for (int r = 0; r < 4; ++r) {
            float mx = fmaxf(fmaxf(acc[mt][0][r], acc[mt][1][r]),
                             fmaxf(acc[mt][2][r], acc[mt][3][r]));
#pragma unroll
            for (int off = 1; off < 16; off <<= 1)
                mx = fmaxf(mx, __shfl_xor(mx, off));
            float s = 0.f;
#pragma unroll
            for (int nt = 0; nt < 4; ++nt) {
                float e = __expf(acc[mt][nt][r] - mx);
                acc[mt][nt][r] = e; s += e;
            }
#pragma unroll
            for (int off = 1; off < 16; off <<= 1)
                s += __shfl_xor(s, off);
            float inv = 1.0f / s;
#pragma unroll
            for (int nt = 0; nt < 4; ++nt) acc[mt][nt][r] *= inv;
        }
    }

    // P: C-layout -> A-layout via wave-private LDS tile (same-wave dep only;
    // compiler's lgkmcnt covers it -- no __syncthreads)
#pragma unroll
    for (int mt = 0; mt < 4; ++mt)
#pragma unroll
        for (int nt = 0; nt < 4; ++nt)
#pragma unroll
            for (int r = 0; r < 4; ++r)
                Plds[wave][mt * 16 + quad * 4 + r][nt * 16 + lr] = (bf16_t)acc[mt][nt][r];

    // PV
    const bf16_t* vs = vtbuf + (size_t)p * 2048;
    bf16x8 vf[2][2];
#pragma unroll
    for (int nt = 0; nt < 2; ++nt)
#pragma unroll
        for (int kt = 0; kt < 2; ++kt)
            vf[nt][kt] = *(const bf16x8*)(vs + (nt * 16 + lr) * 64 + kt * 32 + quad * 8);

#pragma unroll
    for (int mt = 0; mt < 4; ++mt) {
        bf16x8 pf0 = *(const bf16x8*)&Plds[wave][mt * 16 + lr][quad * 8];
        bf16x8 pf1 = *(const bf16x8*)&Plds[wave][mt * 16 + lr][32 + quad * 8];
        floatx4 cacc[2] = {{0.f,0.f,0.f,0.f},{0.f,0.f,0.f,0.f}};
#pragma unroll
        for (int nt = 0; nt < 2; ++nt) {
            cacc[nt] = __builtin_amdgcn_mfma_f32_16x16x32_bf16(pf0, vf[nt][0], cacc[nt], 0, 0, 0);
            cacc[nt] = __builtin_amdgcn_mfma_f32_16x16x32_bf16(pf1, vf[nt][1], cacc[nt], 0, 0, 0);
        }
#pragma unroll
        for (int nt = 0; nt < 2; ++nt)
#pragma unroll
            for (int r = 0; r < 4; ++r) {
                int m = mt * 16 + quad * 4 + r;
                if (m < 49)
                    ctx[((size_t)b_ * 49 + m) * 192 + h * 32 + nt * 16 + lr] = (bf16_t)cacc[nt][r];
            }
    }
}

// ---------------------------------------------------------------------------
extern "C" void kernel_launch(void* const* d_in, const int* in_sizes, int n_in,
                              void* d_out, int out_size, void* d_ws, size_t ws_size,
                              hipStream_t stream)
{
    const float* inp    = (const float*)d_in[0];
    const float* mask   = (const float*)d_in[1];
    const float* g      = (const float*)d_in[2];
    const float* bta    = (const float*)d_in[3];
    const float* qkv_w  = (const float*)d_in[4];
    const float* qkv_b  = (const float*)d_in[5];
    const float* table  = (const float*)d_in[6];
    const int*   rpi    = (const int*)d_in[7];
    const float* proj_w = (const float*)d_in[8];
    const float* proj_b = (const float*)d_in[9];
    const float* lin_w  = (const float*)d_in[10];
    const float* lin_b  = (const float*)d_in[11];
    float* out = (float*)d_out;

    char* ws = (char*)d_ws;
    bf16_t* xw   = (bf16_t*)(ws);                    //  38,535,168 B
    bf16_t* qb   = (bf16_t*)(ws + 38535168);         //  38,535,168 B
    bf16_t* kb   = (bf16_t*)(ws + 77070336);         //  38,535,168 B
    bf16_t* vt   = (bf16_t*)(ws + 115605504);        //  50,331,648 B
    bf16_t* ctxb = (bf16_t*)(ws + 165937152);        //  38,535,168 B
    bf16_t* pob  = (bf16_t*)(ws + 204472320);        //  38,535,168 B
    bf16_t* wcvt = (bf16_t*)(ws + 243007488);        //     368,640 B
    bf16_t* cb2  = (bf16_t*)(ws + 243376128);        //   3,145,728 B  (end 246.5 MB)

    convert_weights<<<720, 256, 0, stream>>>(qkv_w, proj_w, lin_w, wcvt);
    build_cb2<<<6144, 256, 0, stream>>>(table, rpi, mask, cb2);
    ln_window<<<25088, 256, 0, stream>>>(inp, g, bta, xw);
    gemm_bf16<<<dim3(9, 784), 256, 0, stream>>>(xw, wcvt, qkv_b, nullptr,
                                                qb, kb, vt, nullptr, 0);
    attn_mfma<<<3072, 256, 0, stream>>>(qb, kb, vt, cb2, ctxb);
    gemm_bf16<<<dim3(3, 784), 256, 0, stream>>>(ctxb, wcvt + 110592, proj_b, nullptr,
                                                pob, nullptr, nullptr, nullptr, 1);
    gemm_bf16<<<dim3(3, 784), 256, 0, stream>>>(pob, wcvt + 147456, lin_b, inp,
                                                nullptr, nullptr, nullptr, out, 2);
}

// Round 5
// 389.752 us; speedup vs baseline: 2.5772x; 1.2907x over previous
//
#include <hip/hip_runtime.h>
#include <hip/hip_bf16.h>
#include <math.h>

typedef __bf16 bf16_t;
typedef __attribute__((ext_vector_type(8))) __bf16 bf16x8;
typedef __attribute__((ext_vector_type(4))) float floatx4;

#define SCALE 0.17677669529663689f
#define MFMA __builtin_amdgcn_mfma_f32_16x16x32_bf16

// ---------------------------------------------------------------------------
// LayerNorm + cyclic shift (-3,-3) + window partition; fp32 in -> bf16 out
// ---------------------------------------------------------------------------
__global__ __launch_bounds__(256)
void ln_window(const float* __restrict__ x, const float* __restrict__ g,
               const float* __restrict__ bta, bf16_t* __restrict__ xw)
{
    const int wv = threadIdx.x >> 6, lane = threadIdx.x & 63;
    const int t = blockIdx.x * 4 + wv;            // token id, < 100352
    const float* row = x + (size_t)t * 192;
    float v0 = row[lane];
    float v1 = row[lane + 64];
    float v2 = row[lane + 128];
    float s  = v0 + v1 + v2;
    float sq = v0 * v0 + v1 * v1 + v2 * v2;
#pragma unroll
    for (int off = 32; off > 0; off >>= 1) {
        s  += __shfl_down(s, off);
        sq += __shfl_down(sq, off);
    }
    s = __shfl(s, 0); sq = __shfl(sq, 0);
    float mu  = s * (1.0f / 192.0f);
    float var = sq * (1.0f / 192.0f) - mu * mu;
    float inv = rsqrtf(var + 1e-5f);

    int b = t / 3136, p = t - b * 3136;
    int hh = p / 56, ww = p - hh * 56;
    int hs = hh - 3; if (hs < 0) hs += 56;
    int ws = ww - 3; if (ws < 0) ws += 56;
    int wh = hs / 7, ii = hs - wh * 7;
    int wwi = ws / 7, jj = ws - wwi * 7;
    size_t orow = ((size_t)(b * 64 + wh * 8 + wwi) * 49 + ii * 7 + jj) * 192;

    xw[orow + lane]       = (bf16_t)((v0 - mu) * inv * g[lane]       + bta[lane]);
    xw[orow + lane + 64]  = (bf16_t)((v1 - mu) * inv * g[lane + 64]  + bta[lane + 64]);
    xw[orow + lane + 128] = (bf16_t)((v2 - mu) * inv * g[lane + 128] + bta[lane + 128]);
}

// ---------------------------------------------------------------------------
// Weight fp32 -> bf16 conversion (qkv_w | proj_w | lin_w concatenated)
// ---------------------------------------------------------------------------
__global__ __launch_bounds__(256)
void convert_weights(const float* __restrict__ a, const float* __restrict__ b,
                     const float* __restrict__ c, bf16_t* __restrict__ out)
{
    int i = blockIdx.x * 256 + threadIdx.x;   // 184320 total
    if (i < 110592)       out[i] = (bf16_t)a[i];
    else if (i < 147456)  out[i] = (bf16_t)b[i - 110592];
    else                  out[i] = (bf16_t)c[i - 147456];
}

// ---------------------------------------------------------------------------
// Pre-combine rel-pos bias + shift mask into C-fragment-ordered table:
// cb2[wh=win*6+h][mt][lane][nt*4+r]  (bf16); j>=49 -> -1e30
// ---------------------------------------------------------------------------
__global__ __launch_bounds__(256)
void build_cb2(const float* __restrict__ table, const int* __restrict__ rpi,
               const float* __restrict__ mask, bf16_t* __restrict__ cb2)
{
    int i = blockIdx.x * 256 + threadIdx.x;   // 1,572,864 total
    int idx = i & 15, lane = (i >> 4) & 63, mt = (i >> 10) & 3, wh = i >> 12;
    int win = wh / 6, h = wh - win * 6;
    int nt = idx >> 2, r = idx & 3;
    int m = mt * 16 + ((lane >> 4)) * 4 + r;
    int j = nt * 16 + (lane & 15);
    float v;
    if (j >= 49)      v = -1e30f;
    else if (m >= 49) v = 0.0f;
    else              v = table[rpi[m * 49 + j] * 6 + h] + mask[win * 2401 + m * 49 + j];
    cb2[i] = (bf16_t)v;
}

// ---------------------------------------------------------------------------
// Fused per-window kernel: qkv GEMM + attention + proj GEMM.
// One block per window (2048), 6 waves, wave h = head h.
// LDS: 6 regions of 5120 bf16 (10.24 KB) = 60 KB total.
//   region/head: [q 64x40 | k 64x40]  -> overlaid by P 64x72 -> rows 0..31
//   overlaid by vT 32x72 (after P fragments pulled to regs; DS is in-order
//   per wave so no barrier needed for wave-private reuse).
// ctx transposes through lds[0..12800) (2 block barriers) into proj.
// Only global write: proj output scattered to spatial layout (window-reverse).
// ---------------------------------------------------------------------------
__global__ __launch_bounds__(384)
void fused_window(const bf16_t* __restrict__ xw, const bf16_t* __restrict__ wcvt,
                  const float* __restrict__ qkv_b, const float* __restrict__ proj_b,
                  const bf16_t* __restrict__ cb2, bf16_t* __restrict__ pob)
{
    __shared__ __align__(16) bf16_t lds[30720];     // 6 * 5120
    const int tid = threadIdx.x;
    const int h = tid >> 6;                          // head 0..5
    const int lane = tid & 63;
    const int quad = lane >> 4, lr = lane & 15;
    const int w = blockIdx.x;                        // window id 0..2047
    const int wh = (w & 63) * 6 + h;
    bf16_t* R = lds + h * 5120;

    // ---- X A-fragments, held in registers (window rows are contiguous) ----
    const bf16_t* xb = xw + (size_t)w * 49 * 192;
    bf16x8 xf[4][6];
#pragma unroll
    for (int mt = 0; mt < 4; ++mt)
#pragma unroll
        for (int ks = 0; ks < 6; ++ks)
            xf[mt][ks] = *(const bf16x8*)(xb + (size_t)(mt * 16 + lr) * 192 + ks * 32 + quad * 8);

    // ---- Phase A1: q,k = X @ Wq,Wk  (64 tok x 64 cols) ----
    floatx4 acc[4][4];
#pragma unroll
    for (int mt = 0; mt < 4; ++mt)
#pragma unroll
        for (int nt = 0; nt < 4; ++nt) acc[mt][nt] = floatx4{0.f,0.f,0.f,0.f};

#pragma unroll
    for (int ks = 0; ks < 6; ++ks) {
        bf16x8 wf0 = *(const bf16x8*)(wcvt + (size_t)(h * 32 + lr) * 192 + ks * 32 + quad * 8);
        bf16x8 wf1 = *(const bf16x8*)(wcvt + (size_t)(h * 32 + 16 + lr) * 192 + ks * 32 + quad * 8);
        bf16x8 wf2 = *(const bf16x8*)(wcvt + (size_t)(192 + h * 32 + lr) * 192 + ks * 32 + quad * 8);
        bf16x8 wf3 = *(const bf16x8*)(wcvt + (size_t)(192 + h * 32 + 16 + lr) * 192 + ks * 32 + quad * 8);
#pragma unroll
        for (int mt = 0; mt < 4; ++mt) {
            acc[mt][0] = MFMA(xf[mt][ks], wf0, acc[mt][0], 0, 0, 0);
            acc[mt][1] = MFMA(xf[mt][ks], wf1, acc[mt][1], 0, 0, 0);
            acc[mt][2] = MFMA(xf[mt][ks], wf2, acc[mt][2], 0, 0, 0);
            acc[mt][3] = MFMA(xf[mt][ks], wf3, acc[mt][3], 0, 0, 0);
        }
    }
    {
        float bq0 = qkv_b[h * 32 + lr],       bq1 = qkv_b[h * 32 + 16 + lr];
        float bk0 = qkv_b[192 + h * 32 + lr], bk1 = qkv_b[192 + h * 32 + 16 + lr];
#pragma unroll
        for (int mt = 0; mt < 4; ++mt)
#pragma unroll
            for (int r = 0; r < 4; ++r) {
                int tok = mt * 16 + quad * 4 + r;
                R[tok * 40 + lr]             = (bf16_t)((acc[mt][0][r] + bq0) * SCALE);
                R[tok * 40 + 16 + lr]        = (bf16_t)((acc[mt][1][r] + bq1) * SCALE);
                R[2560 + tok * 40 + lr]      = (bf16_t)(acc[mt][2][r] + bk0);
                R[2560 + tok * 40 + 16 + lr] = (bf16_t)(acc[mt][3][r] + bk1);
            }
    }

    // ---- QK^T (64x64, K=32) ----
    bf16x8 qf[4], kf[4];
#pragma unroll
    for (int t = 0; t < 4; ++t) {
        qf[t] = *(const bf16x8*)&R[(t * 16 + lr) * 40 + quad * 8];
        kf[t] = *(const bf16x8*)&R[2560 + (t * 16 + lr) * 40 + quad * 8];
    }
    floatx4 s[4][4];
#pragma unroll
    for (int mt = 0; mt < 4; ++mt)
#pragma unroll
        for (int nt = 0; nt < 4; ++nt) s[mt][nt] = floatx4{0.f,0.f,0.f,0.f};
#pragma unroll
    for (int mt = 0; mt < 4; ++mt)
#pragma unroll
        for (int nt = 0; nt < 4; ++nt)
            s[mt][nt] = MFMA(qf[mt], kf[nt], s[mt][nt], 0, 0, 0);

    // bias + mask (C-frag ordered)
    const bf16_t* cb = cb2 + (((size_t)wh * 4) * 64 + lane) * 16;
#pragma unroll
    for (int mt = 0; mt < 4; ++mt) {
        bf16x8 c0 = *(const bf16x8*)(cb + (size_t)mt * 1024);
        bf16x8 c1 = *(const bf16x8*)(cb + (size_t)mt * 1024 + 8);
#pragma unroll
        for (int r = 0; r < 4; ++r) {
            s[mt][0][r] += (float)c0[r];
            s[mt][1][r] += (float)c0[4 + r];
            s[mt][2][r] += (float)c1[r];
            s[mt][3][r] += (float)c1[4 + r];
        }
    }

    // in-register row softmax (row spread over 16 lr lanes x 4 nt regs)
#pragma unroll
    for (int mt = 0; mt < 4; ++mt) {
#pragma unroll
        for (int r = 0; r < 4; ++r) {
            float mx = fmaxf(fmaxf(s[mt][0][r], s[mt][1][r]),
                             fmaxf(s[mt][2][r], s[mt][3][r]));
#pragma unroll
            for (int off = 1; off < 16; off <<= 1)
                mx = fmaxf(mx, __shfl_xor(mx, off));
            float sum = 0.f;
#pragma unroll
            for (int nt = 0; nt < 4; ++nt) {
                float e = __expf(s[mt][nt][r] - mx);
                s[mt][nt][r] = e; sum += e;
            }
#pragma unroll
            for (int off = 1; off < 16; off <<= 1)
                sum += __shfl_xor(sum, off);
            float inv = 1.0f / sum;
#pragma unroll
            for (int nt = 0; nt < 4; ++nt) s[mt][nt][r] *= inv;
        }
    }

    // ---- P -> LDS (overwrites q/k; wave-private), pull A-frags of P ----
#pragma unroll
    for (int mt = 0; mt < 4; ++mt)
#pragma unroll
        for (int nt = 0; nt < 4; ++nt)
#pragma unroll
            for (int r = 0; r < 4; ++r)
                R[(mt * 16 + quad * 4 + r) * 72 + nt * 16 + lr] = (bf16_t)s[mt][nt][r];
    bf16x8 pf[4][2];
#pragma unroll
    for (int mt = 0; mt < 4; ++mt)
#pragma unroll
        for (int kt = 0; kt < 2; ++kt)
            pf[mt][kt] = *(const bf16x8*)&R[(mt * 16 + lr) * 72 + kt * 32 + quad * 8];

    // ---- Phase A2: v = X @ Wv (64 tok x 32 d) ----
    floatx4 va[4][2];
#pragma unroll
    for (int mt = 0; mt < 4; ++mt) { va[mt][0] = floatx4{0.f,0.f,0.f,0.f}; va[mt][1] = floatx4{0.f,0.f,0.f,0.f}; }
#pragma unroll
    for (int ks = 0; ks < 6; ++ks) {
        bf16x8 wv0 = *(const bf16x8*)(wcvt + (size_t)(384 + h * 32 + lr) * 192 + ks * 32 + quad * 8);
        bf16x8 wv1 = *(const bf16x8*)(wcvt + (size_t)(384 + h * 32 + 16 + lr) * 192 + ks * 32 + quad * 8);
#pragma unroll
        for (int mt = 0; mt < 4; ++mt) {
            va[mt][0] = MFMA(xf[mt][ks], wv0, va[mt][0], 0, 0, 0);
            va[mt][1] = MFMA(xf[mt][ks], wv1, va[mt][1], 0, 0, 0);
        }
    }
    // vT into P region rows 0..31 (P frags already in regs; DS in-order)
    {
        float bv0 = qkv_b[384 + h * 32 + lr], bv1 = qkv_b[384 + h * 32 + 16 + lr];
#pragma unroll
        for (int mt = 0; mt < 4; ++mt)
#pragma unroll
            for (int r = 0; r < 4; ++r) {
                int tok = mt * 16 + quad * 4 + r;
                R[lr * 72 + tok]        = (bf16_t)(va[mt][0][r] + bv0);
                R[(16 + lr) * 72 + tok] = (bf16_t)(va[mt][1][r] + bv1);
            }
    }

    // ---- PV (64 x 32, K=64) ----
    bf16x8 vf[2][2];
#pragma unroll
    for (int nt = 0; nt < 2; ++nt)
#pragma unroll
        for (int kt = 0; kt < 2; ++kt)
            vf[nt][kt] = *(const bf16x8*)&R[(nt * 16 + lr) * 72 + kt * 32 + quad * 8];
    floatx4 c[4][2];
#pragma unroll
    for (int mt = 0; mt < 4; ++mt) { c[mt][0] = floatx4{0.f,0.f,0.f,0.f}; c[mt][1] = floatx4{0.f,0.f,0.f,0.f}; }
#pragma unroll
    for (int mt = 0; mt < 4; ++mt)
#pragma unroll
        for (int nt = 0; nt < 2; ++nt) {
            c[mt][nt] = MFMA(pf[mt][0], vf[nt][0], c[mt][nt], 0, 0, 0);
            c[mt][nt] = MFMA(pf[mt][1], vf[nt][1], c[mt][nt], 0, 0, 0);
        }

    // ---- ctx -> shared [64][200] (overlays head regions 0-2) ----
    __syncthreads();
#pragma unroll
    for (int mt = 0; mt < 4; ++mt)
#pragma unroll
        for (int nt = 0; nt < 2; ++nt)
#pragma unroll
            for (int r = 0; r < 4; ++r)
                lds[(mt * 16 + quad * 4 + r) * 200 + h * 32 + nt * 16 + lr] = (bf16_t)c[mt][nt][r];
    __syncthreads();

    // ---- proj: ctx[64x192] @ proj_w -> cols [h*32, h*32+32) ----
    const bf16_t* pw = wcvt + 110592;
    floatx4 pr[4][2];
#pragma unroll
    for (int mt = 0; mt < 4; ++mt) { pr[mt][0] = floatx4{0.f,0.f,0.f,0.f}; pr[mt][1] = floatx4{0.f,0.f,0.f,0.f}; }
#pragma unroll
    for (int ks = 0; ks < 6; ++ks) {
        bf16x8 w0 = *(const bf16x8*)(pw + (size_t)(h * 32 + lr) * 192 + ks * 32 + quad * 8);
        bf16x8 w1 = *(const bf16x8*)(pw + (size_t)(h * 32 + 16 + lr) * 192 + ks * 32 + quad * 8);
#pragma unroll
        for (int mt = 0; mt < 4; ++mt) {
            bf16x8 af = *(const bf16x8*)&lds[(mt * 16 + lr) * 200 + ks * 32 + quad * 8];
            pr[mt][0] = MFMA(af, w0, pr[mt][0], 0, 0, 0);
            pr[mt][1] = MFMA(af, w1, pr[mt][1], 0, 0, 0);
        }
    }
    // epilogue: bias + window-reverse + unshift scatter (only global write)
    {
        float pb0 = proj_b[h * 32 + lr], pb1 = proj_b[h * 32 + 16 + lr];
        int b = w >> 6, widx = w & 63;
        int whh = widx >> 3, www = widx & 7;
#pragma unroll
        for (int mt = 0; mt < 4; ++mt)
#pragma unroll
            for (int r = 0; r < 4; ++r) {
                int m = mt * 16 + quad * 4 + r;
                if (m < 49) {
                    int ii = m / 7, jj = m - ii * 7;
                    int hs = whh * 7 + ii + 3; if (hs >= 56) hs -= 56;
                    int ws2 = www * 7 + jj + 3; if (ws2 >= 56) ws2 -= 56;
                    size_t base = ((size_t)(b * 3136 + hs * 56 + ws2)) * 192 + h * 32;
                    pob[base + lr]      = (bf16_t)(pr[mt][0][r] + pb0);
                    pob[base + 16 + lr] = (bf16_t)(pr[mt][1][r] + pb1);
                }
            }
    }
}

// ---------------------------------------------------------------------------
// lin GEMM (LDS-free): out = resid + gelu(A @ lin_w^T + b), fp32 out.
// Block: 4 waves, tile 128m x 64n; wave tile 32m x 64n. grid (3, 784).
// ---------------------------------------------------------------------------
__global__ __launch_bounds__(256)
void lin_gemm(const bf16_t* __restrict__ A, const bf16_t* __restrict__ W,
              const float* __restrict__ bias, const float* __restrict__ resid,
              float* __restrict__ out)
{
    const int tid = threadIdx.x;
    const int wave = tid >> 6, lane = tid & 63;
    const int quad = lane >> 4, lr = lane & 15;
    const int n0 = blockIdx.x * 64;
    const int m0 = blockIdx.y * 128 + wave * 32;

    const bf16_t* a0p = A + (size_t)(m0 + lr) * 192 + quad * 8;
    const bf16_t* a1p = A + (size_t)(m0 + 16 + lr) * 192 + quad * 8;
    const bf16_t* w0p = W + (size_t)(n0 + lr) * 192 + quad * 8;
    const bf16_t* w1p = w0p + 16 * 192;
    const bf16_t* w2p = w0p + 32 * 192;
    const bf16_t* w3p = w0p + 48 * 192;

    floatx4 acc[2][4];
#pragma unroll
    for (int mt = 0; mt < 2; ++mt)
#pragma unroll
        for (int nt = 0; nt < 4; ++nt) acc[mt][nt] = floatx4{0.f,0.f,0.f,0.f};

#pragma unroll
    for (int ks = 0; ks < 6; ++ks) {
        bf16x8 af0 = *(const bf16x8*)(a0p + ks * 32);
        bf16x8 af1 = *(const bf16x8*)(a1p + ks * 32);
        bf16x8 wf0 = *(const bf16x8*)(w0p + ks * 32);
        bf16x8 wf1 = *(const bf16x8*)(w1p + ks * 32);
        bf16x8 wf2 = *(const bf16x8*)(w2p + ks * 32);
        bf16x8 wf3 = *(const bf16x8*)(w3p + ks * 32);
        acc[0][0] = MFMA(af0, wf0, acc[0][0], 0, 0, 0);
        acc[1][0] = MFMA(af1, wf0, acc[1][0], 0, 0, 0);
        acc[0][1] = MFMA(af0, wf1, acc[0][1], 0, 0, 0);
        acc[1][1] = MFMA(af1, wf1, acc[1][1], 0, 0, 0);
        acc[0][2] = MFMA(af0, wf2, acc[0][2], 0, 0, 0);
        acc[1][2] = MFMA(af1, wf2, acc[1][2], 0, 0, 0);
        acc[0][3] = MFMA(af0, wf3, acc[0][3], 0, 0, 0);
        acc[1][3] = MFMA(af1, wf3, acc[1][3], 0, 0, 0);
    }

#pragma unroll
    for (int mt = 0; mt < 2; ++mt)
#pragma unroll
    for (int nt = 0; nt < 4; ++nt) {
        int n = n0 + nt * 16 + lr;
        float bv = bias[n];
#pragma unroll
        for (int r = 0; r < 4; ++r) {
            int m = m0 + mt * 16 + quad * 4 + r;
            float val = acc[mt][nt][r] + bv;
            float gx = 0.5f * val * (1.0f + erff(val * 0.70710678118654752f));
            out[(size_t)m * 192 + n] = resid[(size_t)m * 192 + n] + gx;
        }
    }
}

// ---------------------------------------------------------------------------
extern "C" void kernel_launch(void* const* d_in, const int* in_sizes, int n_in,
                              void* d_out, int out_size, void* d_ws, size_t ws_size,
                              hipStream_t stream)
{
    const float* inp    = (const float*)d_in[0];
    const float* mask   = (const float*)d_in[1];
    const float* g      = (const float*)d_in[2];
    const float* bta    = (const float*)d_in[3];
    const float* qkv_w  = (const float*)d_in[4];
    const float* qkv_b  = (const float*)d_in[5];
    const float* table  = (const float*)d_in[6];
    const int*   rpi    = (const int*)d_in[7];
    const float* proj_w = (const float*)d_in[8];
    const float* proj_b = (const float*)d_in[9];
    const float* lin_w  = (const float*)d_in[10];
    const float* lin_b  = (const float*)d_in[11];
    float* out = (float*)d_out;

    char* ws = (char*)d_ws;
    bf16_t* xw   = (bf16_t*)(ws);                 // 38,535,168 B (+64-row slack)
    bf16_t* pob  = (bf16_t*)(ws + 40000000);      // 38,535,168 B
    bf16_t* wcvt = (bf16_t*)(ws + 80000000);      //    368,640 B
    bf16_t* cb2  = (bf16_t*)(ws + 80400000);      //  3,145,728 B  (end ~83.5 MB)

    convert_weights<<<720, 256, 0, stream>>>(qkv_w, proj_w, lin_w, wcvt);
    build_cb2<<<6144, 256, 0, stream>>>(table, rpi, mask, cb2);
    ln_window<<<25088, 256, 0, stream>>>(inp, g, bta, xw);
    fused_window<<<2048, 384, 0, stream>>>(xw, wcvt, qkv_b, proj_b, cb2, pob);
    lin_gemm<<<dim3(3, 784), 256, 0, stream>>>(pob, wcvt + 147456, lin_b, inp, out);
}